// Round 1
// baseline (2352.774 us; speedup 1.0000x reference)
//
#include <hip/hip_runtime.h>
#include <cstddef>
#include <cstdint>

#define D_MODEL 256
#define LQ 19950
#define NBATCH 2
#define NT (NBATCH*LQ)

__device__ __forceinline__ void tok_level(int tok, int& H, int& W, int& loff, int& lvl) {
  if (tok < 15200)      { lvl=0; H=100; W=152; loff=0; }
  else if (tok < 19000) { lvl=1; H=50;  W=76;  loff=15200; }
  else                  { lvl=2; H=25;  W=38;  loff=19000; }
}

// ---------- C[M,Nc] = A[M,K] * B[K,Nc] + rowbias[M], batched over z ----------
__global__ __launch_bounds__(256) void gemm_ab(
    const float* __restrict__ A, const float* __restrict__ B,
    const float* __restrict__ rowbias, float* __restrict__ C,
    int M, int K, int Nc, long strideB, long strideC)
{
  __shared__ float As[16][64];
  __shared__ float Bs[16][64];
  const float* Bp = B + (size_t)blockIdx.z * strideB;
  float* Cp = C + (size_t)blockIdx.z * strideC;
  int tid = threadIdx.x;
  int tx = tid & 15, ty = tid >> 4;
  int m0 = blockIdx.y * 64, n0 = blockIdx.x * 64;
  float acc[4][4] = {{0.f}};
  for (int k0 = 0; k0 < K; k0 += 16) {
    {
      int rr = tid >> 4;        // 0..15
      int kc = tid & 15;
      #pragma unroll
      for (int it = 0; it < 4; ++it) {
        int m = rr + it*16;
        int gm = m0 + m;
        As[kc][m] = (gm < M) ? A[(size_t)gm*K + k0 + kc] : 0.f;
      }
      int r2 = tid >> 6;        // 0..3
      int c2 = tid & 63;
      #pragma unroll
      for (int it = 0; it < 4; ++it) {
        int kk = r2 + it*4;
        int gn = n0 + c2;
        Bs[kk][c2] = (gn < Nc) ? Bp[(size_t)(k0+kk)*Nc + gn] : 0.f;
      }
    }
    __syncthreads();
    #pragma unroll
    for (int kk = 0; kk < 16; ++kk) {
      const float4 a4 = *(const float4*)&As[kk][ty*4];
      const float4 b4 = *(const float4*)&Bs[kk][tx*4];
      float av[4] = {a4.x,a4.y,a4.z,a4.w};
      float bv[4] = {b4.x,b4.y,b4.z,b4.w};
      #pragma unroll
      for (int i=0;i<4;++i)
        #pragma unroll
        for (int j=0;j<4;++j) acc[i][j] += av[i]*bv[j];
    }
    __syncthreads();
  }
  #pragma unroll
  for (int i=0;i<4;++i) {
    int gm = m0 + ty*4 + i;
    if (gm >= M) continue;
    float rb = rowbias ? rowbias[gm] : 0.f;
    #pragma unroll
    for (int j=0;j<4;++j) {
      int gn = n0 + tx*4 + j;
      if (gn < Nc) Cp[(size_t)gm*Nc + gn] = acc[i][j] + rb;
    }
  }
}

// ---------- C[M,Nc] = A[M,K] * B[Nc,K]^T + bias[Nc], optional relu ----------
__global__ __launch_bounds__(256) void gemm_abt(
    const float* __restrict__ A, const float* __restrict__ B,
    const float* __restrict__ bias, float* __restrict__ C,
    int M, int K, int Nc, int relu)
{
  __shared__ float As[16][64];
  __shared__ float Bs[16][64];
  int tid = threadIdx.x;
  int tx = tid & 15, ty = tid >> 4;
  int m0 = blockIdx.y*64, n0 = blockIdx.x*64;
  float acc[4][4] = {{0.f}};
  for (int k0 = 0; k0 < K; k0 += 16) {
    int r = tid >> 2;           // 0..63
    int kq = (tid & 3) * 4;     // 0,4,8,12
    float4 va = make_float4(0.f,0.f,0.f,0.f);
    int gm = m0 + r;
    if (gm < M) va = *(const float4*)&A[(size_t)gm*K + k0 + kq];
    As[kq+0][r]=va.x; As[kq+1][r]=va.y; As[kq+2][r]=va.z; As[kq+3][r]=va.w;
    float4 vb = make_float4(0.f,0.f,0.f,0.f);
    int gn = n0 + r;
    if (gn < Nc) vb = *(const float4*)&B[(size_t)gn*K + k0 + kq];
    Bs[kq+0][r]=vb.x; Bs[kq+1][r]=vb.y; Bs[kq+2][r]=vb.z; Bs[kq+3][r]=vb.w;
    __syncthreads();
    #pragma unroll
    for (int kk=0;kk<16;++kk) {
      const float4 a4 = *(const float4*)&As[kk][ty*4];
      const float4 b4 = *(const float4*)&Bs[kk][tx*4];
      float av[4]={a4.x,a4.y,a4.z,a4.w};
      float bv[4]={b4.x,b4.y,b4.z,b4.w};
      #pragma unroll
      for (int i=0;i<4;++i)
        #pragma unroll
        for (int j=0;j<4;++j) acc[i][j] += av[i]*bv[j];
    }
    __syncthreads();
  }
  #pragma unroll
  for (int i=0;i<4;++i) {
    int gm = m0 + ty*4 + i;
    if (gm >= M) continue;
    #pragma unroll
    for (int j=0;j<4;++j) {
      int gn = n0 + tx*4 + j;
      if (gn < Nc) {
        float v = acc[i][j] + (bias ? bias[gn] : 0.f);
        if (relu) v = fmaxf(v, 0.f);
        C[(size_t)gm*Nc + gn] = v;
      }
    }
  }
}

// ---------- GroupNorm stats: per (n, group of 8 channels) over 8*HW ----------
__global__ __launch_bounds__(256) void gn_reduce(
    const float* __restrict__ s, float* __restrict__ stats, int HW)
{
  int g = blockIdx.x, n = blockIdx.y;
  const float* base = s + ((size_t)n*D_MODEL + g*8) * HW;
  int total = 8*HW;
  float sum=0.f, sq=0.f;
  for (int i = threadIdx.x; i < total; i += 256) {
    float v = base[i];
    sum += v; sq += v*v;
  }
  #pragma unroll
  for (int m=32;m;m>>=1){ sum += __shfl_xor(sum,m,64); sq += __shfl_xor(sq,m,64); }
  __shared__ float s1[4], s2[4];
  int w = threadIdx.x >> 6;
  if ((threadIdx.x & 63) == 0) { s1[w]=sum; s2[w]=sq; }
  __syncthreads();
  if (threadIdx.x == 0) {
    float S = s1[0]+s1[1]+s1[2]+s1[3];
    float Q = s2[0]+s2[1]+s2[2]+s2[3];
    float inv = 1.f/(float)total;
    float mu = S*inv;
    float var = Q*inv - mu*mu;
    stats[((size_t)n*32+g)*2]   = mu;
    stats[((size_t)n*32+g)*2+1] = rsqrtf(var + 1e-5f);
  }
}

// ---------- apply GN + transpose (n,o,hw) -> src[(n*LQ+loff+hw)*256+o] ----------
__global__ __launch_bounds__(256) void gn_apply(
    const float* __restrict__ s, const float* __restrict__ stats,
    const float* __restrict__ gw, const float* __restrict__ gb,
    float* __restrict__ src, int HW, int loff)
{
  __shared__ float T[32][33];
  int tx = threadIdx.x & 31, ty = threadIdx.x >> 5;  // ty 0..7
  int hw0 = blockIdx.x*32, o0 = blockIdx.y*32, n = blockIdx.z;
  const float* base = s + (size_t)n*D_MODEL*HW;
  #pragma unroll
  for (int it=0; it<4; ++it) {
    int ol = ty + it*8;
    int o = o0 + ol;
    int hw = hw0 + tx;
    float v = 0.f;
    if (hw < HW) {
      int grp = o >> 3;
      float mu   = stats[((size_t)n*32+grp)*2];
      float rstd = stats[((size_t)n*32+grp)*2+1];
      v = (base[(size_t)o*HW + hw] - mu)*rstd*gw[o] + gb[o];
    }
    T[ol][tx] = v;
  }
  __syncthreads();
  #pragma unroll
  for (int it=0; it<4; ++it) {
    int tl = ty + it*8;
    int tok = hw0 + tl;
    if (tok < HW) {
      src[((size_t)n*LQ + loff + tok)*D_MODEL + o0 + tx] = T[tx][tl];
    }
  }
}

// ---------- q = src + sine_pos + level_embed ----------
__global__ __launch_bounds__(256) void compute_q(
    const float* __restrict__ src, const float* __restrict__ level_embed,
    float* __restrict__ q)
{
  int row = blockIdx.x;          // n*LQ + tok
  int d = threadIdx.x;
  int tok = row % LQ;
  int H,W,loff,lvl; tok_level(tok,H,W,loff,lvl);
  int hw = tok - loff;
  int i = hw / W, j = hw % W;
  const float TWO_PI = 6.28318530717958647692f;
  float yv = (float)(i+1) / ((float)H + 1e-6f) * TWO_PI;
  float xv = (float)(j+1) / ((float)W + 1e-6f) * TWO_PI;
  int m = (d & 127) >> 1;
  float t = powf(10000.0f, (float)m * (1.0f/64.0f));
  float ang = ((d < 128) ? yv : xv) / t;
  float pe = (d & 1) ? cosf(ang) : sinf(ang);
  size_t idx = (size_t)row*D_MODEL + d;
  q[idx] = src[idx] + pe + level_embed[lvl*D_MODEL + d];
}

// ---------- softmax over groups of 12 ----------
__global__ __launch_bounds__(256) void softmax12(float* __restrict__ aw)
{
  int g = blockIdx.x*256 + threadIdx.x;
  if (g >= NT*8) return;
  float* p = aw + (size_t)(g >> 3)*96 + (g & 7)*12;
  float m = p[0];
  #pragma unroll
  for (int i=1;i<12;++i) m = fmaxf(m, p[i]);
  float e[12]; float s = 0.f;
  #pragma unroll
  for (int i=0;i<12;++i){ e[i] = expf(p[i]-m); s += e[i]; }
  float inv = 1.f/s;
  #pragma unroll
  for (int i=0;i<12;++i) p[i] = e[i]*inv;
}

// ---------- deformable attention sampling ----------
__global__ __launch_bounds__(256) void deform_sample(
    const float* __restrict__ value, const float* __restrict__ offb,
    const float* __restrict__ awb, float* __restrict__ accb)
{
  int idx = blockIdx.x*256 + threadIdx.x;
  if (idx >= NT*8*4) return;
  int quarter = idx & 3;
  int h = (idx >> 2) & 7;
  int row = idx >> 5;            // n*LQ + tok
  int tok = row % LQ;
  int n = row / LQ;
  int Ht,Wt,lofft,lvlt; tok_level(tok,Ht,Wt,lofft,lvlt);
  int hw = tok - lofft;
  int ti = hw / Wt, tj = hw % Wt;
  float gxr = ((float)tj + 0.5f) / (float)Wt;
  float gyr = ((float)ti + 0.5f) / (float)Ht;
  const float* offr = offb + (size_t)row*192 + h*24;
  const float* awr  = awb  + (size_t)row*96  + h*12;
  float acc[8] = {0.f,0.f,0.f,0.f,0.f,0.f,0.f,0.f};
  const int HH[3]={100,50,25}, WW[3]={152,76,38}, OO[3]={0,15200,19000};
  int chbase = h*32 + quarter*8;
  #pragma unroll
  for (int lvl=0; lvl<3; ++lvl) {
    const int H=HH[lvl], W=WW[lvl], lo=OO[lvl];
    #pragma unroll
    for (int p=0; p<4; ++p) {
      float ox = offr[lvl*8 + p*2];
      float oy = offr[lvl*8 + p*2 + 1];
      float a  = awr[lvl*4 + p];
      float locx = gxr + ox / (float)W;
      float locy = gyr + oy / (float)H;
      float gx = 2.f*locx - 1.f;
      float gy = 2.f*locy - 1.f;
      float x = ((gx + 1.f) * (float)W - 1.f) * 0.5f;
      float y = ((gy + 1.f) * (float)H - 1.f) * 0.5f;
      float x0f = floorf(x), y0f = floorf(y);
      float wx = x - x0f, wy = y - y0f;
      int x0 = (int)x0f, y0 = (int)y0f;
      float tw[4] = { (1.f-wx)*(1.f-wy)*a, wx*(1.f-wy)*a, (1.f-wx)*wy*a, wx*wy*a };
      #pragma unroll
      for (int t=0; t<4; ++t) {
        int xi = x0 + (t & 1), yi = y0 + (t >> 1);
        if (xi >= 0 && xi < W && yi >= 0 && yi < H) {
          const float w = tw[t];
          const float* vr = value + ((size_t)(n*LQ + lo + yi*W + xi)*D_MODEL + chbase);
          float4 v0 = *(const float4*)vr;
          float4 v1 = *(const float4*)(vr+4);
          acc[0] += w*v0.x; acc[1] += w*v0.y; acc[2] += w*v0.z; acc[3] += w*v0.w;
          acc[4] += w*v1.x; acc[5] += w*v1.y; acc[6] += w*v1.z; acc[7] += w*v1.w;
        }
      }
    }
  }
  float* o = accb + (size_t)row*D_MODEL + chbase;
  *(float4*)o     = make_float4(acc[0],acc[1],acc[2],acc[3]);
  *(float4*)(o+4) = make_float4(acc[4],acc[5],acc[6],acc[7]);
}

// ---------- out = LN(A+B)*g+b, row length 256, one wave per row ----------
__global__ __launch_bounds__(256) void ln_add(
    const float* __restrict__ A, const float* __restrict__ B,
    const float* __restrict__ g, const float* __restrict__ b,
    float* __restrict__ out, int rows)
{
  int wid = (blockIdx.x * 256 + threadIdx.x) >> 6;
  int lane = threadIdx.x & 63;
  if (wid >= rows) return;
  size_t base = (size_t)wid * D_MODEL;
  float4 va = *(const float4*)&A[base + lane*4];
  float4 vb = *(const float4*)&B[base + lane*4];
  float v[4] = {va.x+vb.x, va.y+vb.y, va.z+vb.z, va.w+vb.w};
  float s = v[0]+v[1]+v[2]+v[3];
  #pragma unroll
  for (int m=32; m; m>>=1) s += __shfl_xor(s, m, 64);
  float mu = s * (1.f/256.f);
  float qq = 0.f;
  #pragma unroll
  for (int i=0;i<4;++i){ float d=v[i]-mu; qq += d*d; }
  #pragma unroll
  for (int m=32; m; m>>=1) qq += __shfl_xor(qq, m, 64);
  float rstd = rsqrtf(qq*(1.f/256.f) + 1e-5f);
  #pragma unroll
  for (int i=0;i<4;++i){
    int d = lane*4+i;
    out[base+d] = (v[i]-mu)*rstd*g[d] + b[d];
  }
}

// ---------- point head bilinear sample from level-0 tokens ----------
__global__ __launch_bounds__(256) void point_sample(
    const float* __restrict__ x2, const float* __restrict__ pc,
    float* __restrict__ pf)
{
  int pidx = blockIdx.x;          // 0..1999
  int n = pidx / 1000;
  float px = pc[(size_t)pidx*2], py = pc[(size_t)pidx*2+1];
  float gx = 2.f*px - 1.f, gy = 2.f*py - 1.f;
  float x = ((gx+1.f)*152.f - 1.f)*0.5f;
  float y = ((gy+1.f)*100.f - 1.f)*0.5f;
  float x0f=floorf(x), y0f=floorf(y);
  float wx=x-x0f, wy=y-y0f;
  int x0=(int)x0f, y0=(int)y0f;
  int d = threadIdx.x;
  float accv = 0.f;
  #pragma unroll
  for (int t=0;t<4;++t) {
    int xi = x0 + (t&1), yi = y0 + (t>>1);
    float w = ((t&1)?wx:(1.f-wx)) * ((t>>1)?wy:(1.f-wy));
    if (xi>=0 && xi<152 && yi>=0 && yi<100) {
      accv += w * x2[((size_t)(n*LQ + yi*152 + xi))*D_MODEL + d];
    }
  }
  pf[(size_t)pidx*D_MODEL + d] = accv;
}

__global__ void copy_gt(const int* __restrict__ gt, float* __restrict__ out, int nels)
{
  int i = blockIdx.x*256 + threadIdx.x;
  if (i < nels) out[i] = (float)gt[i];
}

extern "C" void kernel_launch(void* const* d_in, const int* in_sizes, int n_in,
                              void* d_out, int out_size, void* d_ws, size_t ws_size,
                              hipStream_t stream)
{
  const float* feat[3]  = {(const float*)d_in[0], (const float*)d_in[1], (const float*)d_in[2]};
  const float* pc       = (const float*)d_in[3];
  const int*   gt       = (const int*)d_in[4];
  const float* projw[3] = {(const float*)d_in[5],  (const float*)d_in[9],  (const float*)d_in[13]};
  const float* projb[3] = {(const float*)d_in[6],  (const float*)d_in[10], (const float*)d_in[14]};
  const float* gng[3]   = {(const float*)d_in[7],  (const float*)d_in[11], (const float*)d_in[15]};
  const float* gnb[3]   = {(const float*)d_in[8],  (const float*)d_in[12], (const float*)d_in[16]};
  const float* level_embed = (const float*)d_in[17];
  const float* w_off  = (const float*)d_in[18];
  const float* b_off  = (const float*)d_in[19];
  const float* w_attn = (const float*)d_in[20];
  const float* b_attn = (const float*)d_in[21];
  const float* w_val  = (const float*)d_in[22];
  const float* b_val  = (const float*)d_in[23];
  const float* w_out  = (const float*)d_in[24];
  const float* b_out  = (const float*)d_in[25];
  const float* ln1g   = (const float*)d_in[26];
  const float* ln1b   = (const float*)d_in[27];
  const float* ln2g   = (const float*)d_in[28];
  const float* ln2b   = (const float*)d_in[29];
  const float* wff1   = (const float*)d_in[30];
  const float* bff1   = (const float*)d_in[31];
  const float* wff2   = (const float*)d_in[32];
  const float* bff2   = (const float*)d_in[33];
  const float* fcw    = (const float*)d_in[34];
  const float* fcb    = (const float*)d_in[35];

  // workspace layout (floats); total ~52.35M floats ~= 209.4 MB
  float* ws     = (float*)d_ws;
  float* s_tmp  = ws;                       // 10,214,400 (level proj out / q / attn_out / ff out)
  float* srcb   = s_tmp  + 10214400;        // 10,214,400 (src, later x2)
  float* valueb = srcb   + 10214400;        // 10,214,400 (value, later x)
  float* offbuf = valueb + 10214400;        //  7,660,800
  float* awbuf  = offbuf + 7660800;         //  3,830,400
  float* accb   = awbuf  + 3830400;         // 10,214,400 (acc / ff hidden / pf)
  float* stats  = accb   + 10214400;        //        128

  const int HWs[3]  = {15200, 3800, 950};
  const int Cins[3] = {512, 1024, 2048};
  const int LOFF[3] = {0, 15200, 19000};

  // 1) per-level projection + groupnorm + transpose into token-major src
  for (int l = 0; l < 3; ++l) {
    int HW = HWs[l], K = Cins[l];
    gemm_ab<<<dim3((HW+63)/64, 4, NBATCH), 256, 0, stream>>>(
        projw[l], feat[l], projb[l], s_tmp, D_MODEL, K, HW,
        (long)K*HW, (long)D_MODEL*HW);
    gn_reduce<<<dim3(32, NBATCH), 256, 0, stream>>>(s_tmp, stats, HW);
    gn_apply<<<dim3((HW+31)/32, 8, NBATCH), 256, 0, stream>>>(
        s_tmp, stats, gng[l], gnb[l], srcb, HW, LOFF[l]);
  }

  // 2) q = src + pos (into s_tmp)
  compute_q<<<NT, 256, 0, stream>>>(srcb, level_embed, s_tmp);

  // 3) value / offsets / attention weights
  int gy = (NT + 63) / 64;
  gemm_abt<<<dim3(4, gy), 256, 0, stream>>>(srcb,  w_val,  b_val,  valueb, NT, 256, 256, 0);
  gemm_abt<<<dim3(3, gy), 256, 0, stream>>>(s_tmp, w_off,  b_off,  offbuf, NT, 256, 192, 0);
  gemm_abt<<<dim3(2, gy), 256, 0, stream>>>(s_tmp, w_attn, b_attn, awbuf,  NT, 256,  96, 0);
  softmax12<<<(NT*8 + 255)/256, 256, 0, stream>>>(awbuf);

  // 4) deformable sampling -> acc
  deform_sample<<<(NT*8*4 + 255)/256, 256, 0, stream>>>(valueb, offbuf, awbuf, accb);

  // 5) out-proj (-> s_tmp) ; x = LN(src + attn) -> valueb
  gemm_abt<<<dim3(4, gy), 256, 0, stream>>>(accb, w_out, b_out, s_tmp, NT, 256, 256, 0);
  ln_add<<<(NT+3)/4, 256, 0, stream>>>(srcb, s_tmp, ln1g, ln1b, valueb, NT);

  // 6) FFN chunked: h(relu) -> accb ; y -> s_tmp
  for (int c0 = 0; c0 < NT; c0 += 8192) {
    int mc = NT - c0; if (mc > 8192) mc = 8192;
    int gyc = (mc + 63) / 64;
    gemm_abt<<<dim3(16, gyc), 256, 0, stream>>>(
        valueb + (size_t)c0*256, wff1, bff1, accb, mc, 256, 1024, 1);
    gemm_abt<<<dim3(4, gyc), 256, 0, stream>>>(
        accb, wff2, bff2, s_tmp + (size_t)c0*256, mc, 1024, 256, 0);
  }

  // 7) x2 = LN(x + y) -> srcb
  ln_add<<<(NT+3)/4, 256, 0, stream>>>(valueb, s_tmp, ln2g, ln2b, srcb, NT);

  // 8) point bilinear -> pf (accb), fc GEMM -> d_out, gt tail
  point_sample<<<2000, 256, 0, stream>>>(srcb, pc, accb);
  gemm_abt<<<dim3(12544/64, (2000+63)/64), 256, 0, stream>>>(
      accb, fcw, fcb, (float*)d_out, 2000, 256, 12544, 1);
  copy_gt<<<8, 256, 0, stream>>>(gt, (float*)d_out + (size_t)2000*12544, 2000);
}

// Round 2
// 920.388 us; speedup vs baseline: 2.5563x; 2.5563x over previous
//
#include <hip/hip_runtime.h>
#include <cstddef>
#include <cstdint>

#define D_MODEL 256
#define LQ 19950
#define NBATCH 2
#define NT (NBATCH*LQ)

typedef short  bf16x8 __attribute__((ext_vector_type(8)));
typedef float  f32x4  __attribute__((ext_vector_type(4)));
typedef unsigned short u16x8 __attribute__((ext_vector_type(8)));

__device__ __forceinline__ unsigned short f2b(float f) {
  unsigned u = __float_as_uint(f);
  u += 0x7fff + ((u >> 16) & 1);          // RNE
  return (unsigned short)(u >> 16);
}
__device__ __forceinline__ float b2f(unsigned short s) {
  return __uint_as_float(((unsigned)s) << 16);
}
__device__ __forceinline__ bf16x8 pack8(float4 a, float4 b) {
  bf16x8 r;
  r[0]=(short)f2b(a.x); r[1]=(short)f2b(a.y); r[2]=(short)f2b(a.z); r[3]=(short)f2b(a.w);
  r[4]=(short)f2b(b.x); r[5]=(short)f2b(b.y); r[6]=(short)f2b(b.z); r[7]=(short)f2b(b.w);
  return r;
}

__device__ __forceinline__ void tok_level(int tok, int& H, int& W, int& loff, int& lvl) {
  if (tok < 15200)      { lvl=0; H=100; W=152; loff=0; }
  else if (tok < 19000) { lvl=1; H=50;  W=76;  loff=15200; }
  else                  { lvl=2; H=25;  W=38;  loff=19000; }
}

// ================= unified bf16-MFMA GEMM =================
// C[M,N] = A[M,K] * B + bias (+relu). A: fp32 or bf16 (ABF).
// B always fp32 source: BKN=false -> B[N,K] row-major (B^T form, weights)
//                       BKN=true  -> B[K,N] row-major (proj feature maps)
// C: fp32 or bf16 (CBF). ROWBIAS: bias indexed by M (proj), else by N.
// tile 64x64, BK=64, 256 threads = 4 waves (2x2), each wave 32x32 via 2x2
// mfma_f32_16x16x32_bf16 fragments.
template<bool ABF, bool BKN, bool CBF, bool RELU, bool ROWBIAS>
__global__ __launch_bounds__(256) void mgemm(
    const void* __restrict__ Av, const float* __restrict__ Bv,
    const float* __restrict__ bias, void* __restrict__ Cv,
    int M, int N, int K, int lda, int ldb, long sB, long sC)
{
  __shared__ unsigned short As[64][72];
  __shared__ unsigned short Bs[64][72];
  const int tid = threadIdx.x;
  const float* Bp = Bv + (size_t)blockIdx.z * sB;
  const int n0 = blockIdx.x * 64, m0 = blockIdx.y * 64;
  const int lane = tid & 63;
  const int wave = tid >> 6;
  const int l15 = lane & 15, q = lane >> 4;
  const int m_off = (wave >> 1) * 32, n_off = (wave & 1) * 32;
  f32x4 acc[2][2] = {};

  for (int k0 = 0; k0 < K; k0 += 64) {
    // ---- stage A (convert fp32->bf16 if needed) ----
    {
      int row = tid >> 2, kc = (tid & 3) * 8;
      int gm = m0 + row;
      bf16x8 v0 = (bf16x8)0, v1 = (bf16x8)0;
      if (gm < M) {
        if constexpr (ABF) {
          const unsigned short* A = (const unsigned short*)Av;
          v0 = *(const bf16x8*)&A[(size_t)gm*lda + k0 + kc];
          v1 = *(const bf16x8*)&A[(size_t)gm*lda + k0 + kc + 32];
        } else {
          const float* A = (const float*)Av;
          const float* p = &A[(size_t)gm*lda + k0 + kc];
          v0 = pack8(*(const float4*)p,      *(const float4*)(p+4));
          v1 = pack8(*(const float4*)(p+32), *(const float4*)(p+36));
        }
      }
      *(bf16x8*)&As[row][kc]    = v0;
      *(bf16x8*)&As[row][kc+32] = v1;
    }
    // ---- stage B ----
    if constexpr (!BKN) {
      int row = tid >> 2, kc = (tid & 3) * 8;
      int gn = n0 + row;
      bf16x8 v0 = (bf16x8)0, v1 = (bf16x8)0;
      if (gn < N) {
        const float* p = &Bp[(size_t)gn*ldb + k0 + kc];
        v0 = pack8(*(const float4*)p,      *(const float4*)(p+4));
        v1 = pack8(*(const float4*)(p+32), *(const float4*)(p+36));
      }
      *(bf16x8*)&Bs[row][kc]    = v0;
      *(bf16x8*)&Bs[row][kc+32] = v1;
    } else {
      int kr = tid >> 3, nc = (tid & 7) * 8;
      #pragma unroll
      for (int half = 0; half < 2; ++half) {
        int kk = kr + half*32;
        const float* p = &Bp[(size_t)(k0+kk)*ldb + n0 + nc];
        float v[8];
        if (n0 + nc + 7 < N) {
          float2 a0 = *(const float2*)p,     a1 = *(const float2*)(p+2);
          float2 a2 = *(const float2*)(p+4), a3 = *(const float2*)(p+6);
          v[0]=a0.x; v[1]=a0.y; v[2]=a1.x; v[3]=a1.y;
          v[4]=a2.x; v[5]=a2.y; v[6]=a3.x; v[7]=a3.y;
        } else {
          #pragma unroll
          for (int i=0;i<8;++i) v[i] = (n0+nc+i < N) ? p[i] : 0.f;
        }
        #pragma unroll
        for (int i=0;i<8;++i) Bs[nc+i][kk] = f2b(v[i]);
      }
    }
    __syncthreads();
    #pragma unroll
    for (int s = 0; s < 2; ++s) {
      bf16x8 a0 = *(const bf16x8*)&As[m_off      + l15][s*32 + q*8];
      bf16x8 a1 = *(const bf16x8*)&As[m_off + 16 + l15][s*32 + q*8];
      bf16x8 b0 = *(const bf16x8*)&Bs[n_off      + l15][s*32 + q*8];
      bf16x8 b1 = *(const bf16x8*)&Bs[n_off + 16 + l15][s*32 + q*8];
      acc[0][0] = __builtin_amdgcn_mfma_f32_16x16x32_bf16(a0, b0, acc[0][0], 0,0,0);
      acc[0][1] = __builtin_amdgcn_mfma_f32_16x16x32_bf16(a0, b1, acc[0][1], 0,0,0);
      acc[1][0] = __builtin_amdgcn_mfma_f32_16x16x32_bf16(a1, b0, acc[1][0], 0,0,0);
      acc[1][1] = __builtin_amdgcn_mfma_f32_16x16x32_bf16(a1, b1, acc[1][1], 0,0,0);
    }
    __syncthreads();
  }
  // ---- epilogue: C layout col=lane&15, row=(lane>>4)*4+reg ----
  float* Cf = (float*)Cv + (size_t)blockIdx.z * sC;
  unsigned short* Cb = (unsigned short*)Cv + (size_t)blockIdx.z * sC;
  #pragma unroll
  for (int r = 0; r < 2; ++r) {
    #pragma unroll
    for (int c = 0; c < 2; ++c) {
      #pragma unroll
      for (int v = 0; v < 4; ++v) {
        int gm = m0 + m_off + r*16 + q*4 + v;
        int gn = n0 + n_off + c*16 + l15;
        if (gm < M && gn < N) {
          float o = acc[r][c][v];
          if (bias) o += ROWBIAS ? bias[gm] : bias[gn];
          if (RELU) o = fmaxf(o, 0.f);
          if constexpr (CBF) Cb[(size_t)gm*N + gn] = f2b(o);
          else               Cf[(size_t)gm*N + gn] = o;
        }
      }
    }
  }
}

// ---------- GroupNorm stats: per (n, group of 8 channels) over 8*HW ----------
__global__ __launch_bounds__(256) void gn_reduce(
    const float* __restrict__ s, float* __restrict__ stats, int HW)
{
  int g = blockIdx.x, n = blockIdx.y;
  const float* base = s + ((size_t)n*D_MODEL + g*8) * HW;
  int total = 8*HW;
  float sum=0.f, sq=0.f;
  for (int i = threadIdx.x; i < total; i += 256) {
    float v = base[i];
    sum += v; sq += v*v;
  }
  #pragma unroll
  for (int m=32;m;m>>=1){ sum += __shfl_xor(sum,m,64); sq += __shfl_xor(sq,m,64); }
  __shared__ float s1[4], s2[4];
  int w = threadIdx.x >> 6;
  if ((threadIdx.x & 63) == 0) { s1[w]=sum; s2[w]=sq; }
  __syncthreads();
  if (threadIdx.x == 0) {
    float S = s1[0]+s1[1]+s1[2]+s1[3];
    float Q = s2[0]+s2[1]+s2[2]+s2[3];
    float inv = 1.f/(float)total;
    float mu = S*inv;
    float var = Q*inv - mu*mu;
    stats[((size_t)n*32+g)*2]   = mu;
    stats[((size_t)n*32+g)*2+1] = rsqrtf(var + 1e-5f);
  }
}

// ---------- apply GN + transpose (n,o,hw) -> src[(n*LQ+loff+hw)*256+o] ----------
__global__ __launch_bounds__(256) void gn_apply(
    const float* __restrict__ s, const float* __restrict__ stats,
    const float* __restrict__ gw, const float* __restrict__ gb,
    float* __restrict__ src, int HW, int loff)
{
  __shared__ float T[32][33];
  int tx = threadIdx.x & 31, ty = threadIdx.x >> 5;
  int hw0 = blockIdx.x*32, o0 = blockIdx.y*32, n = blockIdx.z;
  const float* base = s + (size_t)n*D_MODEL*HW;
  #pragma unroll
  for (int it=0; it<4; ++it) {
    int ol = ty + it*8;
    int o = o0 + ol;
    int hw = hw0 + tx;
    float v = 0.f;
    if (hw < HW) {
      int grp = o >> 3;
      float mu   = stats[((size_t)n*32+grp)*2];
      float rstd = stats[((size_t)n*32+grp)*2+1];
      v = (base[(size_t)o*HW + hw] - mu)*rstd*gw[o] + gb[o];
    }
    T[ol][tx] = v;
  }
  __syncthreads();
  #pragma unroll
  for (int it=0; it<4; ++it) {
    int tl = ty + it*8;
    int tok = hw0 + tl;
    if (tok < HW) {
      src[((size_t)n*LQ + loff + tok)*D_MODEL + o0 + tx] = T[tx][tl];
    }
  }
}

// ---------- q = bf16(src + sine_pos + level_embed) ----------
__global__ __launch_bounds__(256) void compute_q(
    const float* __restrict__ src, const float* __restrict__ level_embed,
    unsigned short* __restrict__ q)
{
  int row = blockIdx.x;
  int d = threadIdx.x;
  int tok = row % LQ;
  int H,W,loff,lvl; tok_level(tok,H,W,loff,lvl);
  int hw = tok - loff;
  int i = hw / W, j = hw % W;
  const float TWO_PI = 6.28318530717958647692f;
  float yv = (float)(i+1) / ((float)H + 1e-6f) * TWO_PI;
  float xv = (float)(j+1) / ((float)W + 1e-6f) * TWO_PI;
  int m = (d & 127) >> 1;
  float t = powf(10000.0f, (float)m * (1.0f/64.0f));
  float ang = ((d < 128) ? yv : xv) / t;
  float pe = (d & 1) ? cosf(ang) : sinf(ang);
  size_t idx = (size_t)row*D_MODEL + d;
  q[idx] = f2b(src[idx] + pe + level_embed[lvl*D_MODEL + d]);
}

// ---------- deformable sampling (bf16 value, softmax fused) ----------
__global__ __launch_bounds__(256) void deform_sample(
    const unsigned short* __restrict__ value, const float* __restrict__ offb,
    const float* __restrict__ awb, unsigned short* __restrict__ accb)
{
  int idx = blockIdx.x*256 + threadIdx.x;
  if (idx >= NT*8*4) return;
  int quarter = idx & 3;
  int h = (idx >> 2) & 7;
  int row = idx >> 5;
  int tok = row % LQ;
  int n = row / LQ;
  int Ht,Wt,lofft,lvlt; tok_level(tok,Ht,Wt,lofft,lvlt);
  int hw = tok - lofft;
  int ti = hw / Wt, tj = hw % Wt;
  float gxr = ((float)tj + 0.5f) / (float)Wt;
  float gyr = ((float)ti + 0.5f) / (float)Ht;
  const float* offr = offb + (size_t)row*192 + h*24;
  const float* awr  = awb  + (size_t)row*96  + h*12;
  // softmax over the 12 raw logits
  float lg[12];
  float mx = -1e30f;
  #pragma unroll
  for (int i=0;i<12;++i){ lg[i]=awr[i]; mx = fmaxf(mx, lg[i]); }
  float ssum = 0.f;
  #pragma unroll
  for (int i=0;i<12;++i){ lg[i] = __expf(lg[i]-mx); ssum += lg[i]; }
  float sinv = 1.f/ssum;
  float acc[8] = {0.f,0.f,0.f,0.f,0.f,0.f,0.f,0.f};
  const int HH[3]={100,50,25}, WW[3]={152,76,38}, OO[3]={0,15200,19000};
  int chbase = h*32 + quarter*8;
  #pragma unroll
  for (int lvl=0; lvl<3; ++lvl) {
    const int H=HH[lvl], W=WW[lvl], lo=OO[lvl];
    #pragma unroll
    for (int p=0; p<4; ++p) {
      float ox = offr[lvl*8 + p*2];
      float oy = offr[lvl*8 + p*2 + 1];
      float a  = lg[lvl*4 + p] * sinv;
      float locx = gxr + ox / (float)W;
      float locy = gyr + oy / (float)H;
      float x = ((2.f*locx) * (float)W - 1.f) * 0.5f;
      float y = ((2.f*locy) * (float)H - 1.f) * 0.5f;
      float x0f = floorf(x), y0f = floorf(y);
      float wx = x - x0f, wy = y - y0f;
      int x0 = (int)x0f, y0 = (int)y0f;
      float tw[4] = { (1.f-wx)*(1.f-wy)*a, wx*(1.f-wy)*a, (1.f-wx)*wy*a, wx*wy*a };
      #pragma unroll
      for (int t=0; t<4; ++t) {
        int xi = x0 + (t & 1), yi = y0 + (t >> 1);
        if (xi >= 0 && xi < W && yi >= 0 && yi < H) {
          const float w = tw[t];
          const unsigned short* vr = value + ((size_t)(n*LQ + lo + yi*W + xi)*D_MODEL + chbase);
          u16x8 v = *(const u16x8*)vr;
          #pragma unroll
          for (int jj=0;jj<8;++jj) acc[jj] += w * b2f(v[jj]);
        }
      }
    }
  }
  unsigned short* o = accb + (size_t)row*D_MODEL + chbase;
  u16x8 ov;
  #pragma unroll
  for (int jj=0;jj<8;++jj) ov[jj] = f2b(acc[jj]);
  *(u16x8*)o = ov;
}

// ---------- out = LN(A+B)*g+b, row length 256, one wave per row ----------
__global__ __launch_bounds__(256) void ln_add(
    const float* __restrict__ A, const float* __restrict__ B,
    const float* __restrict__ g, const float* __restrict__ b,
    float* __restrict__ out, int rows)
{
  int wid = (blockIdx.x * 256 + threadIdx.x) >> 6;
  int lane = threadIdx.x & 63;
  if (wid >= rows) return;
  size_t base = (size_t)wid * D_MODEL;
  float4 va = *(const float4*)&A[base + lane*4];
  float4 vb = *(const float4*)&B[base + lane*4];
  float v[4] = {va.x+vb.x, va.y+vb.y, va.z+vb.z, va.w+vb.w};
  float s = v[0]+v[1]+v[2]+v[3];
  #pragma unroll
  for (int m=32; m; m>>=1) s += __shfl_xor(s, m, 64);
  float mu = s * (1.f/256.f);
  float qq = 0.f;
  #pragma unroll
  for (int i=0;i<4;++i){ float d=v[i]-mu; qq += d*d; }
  #pragma unroll
  for (int m=32; m; m>>=1) qq += __shfl_xor(qq, m, 64);
  float rstd = rsqrtf(qq*(1.f/256.f) + 1e-5f);
  #pragma unroll
  for (int i=0;i<4;++i){
    int d = lane*4+i;
    out[base+d] = (v[i]-mu)*rstd*g[d] + b[d];
  }
}

// ---------- point head bilinear sample from level-0 tokens ----------
__global__ __launch_bounds__(256) void point_sample(
    const float* __restrict__ x2, const float* __restrict__ pc,
    float* __restrict__ pf)
{
  int pidx = blockIdx.x;
  int n = pidx / 1000;
  float px = pc[(size_t)pidx*2], py = pc[(size_t)pidx*2+1];
  float x = ((2.f*px)*152.f - 1.f)*0.5f;
  float y = ((2.f*py)*100.f - 1.f)*0.5f;
  float x0f=floorf(x), y0f=floorf(y);
  float wx=x-x0f, wy=y-y0f;
  int x0=(int)x0f, y0=(int)y0f;
  int d = threadIdx.x;
  float accv = 0.f;
  #pragma unroll
  for (int t=0;t<4;++t) {
    int xi = x0 + (t&1), yi = y0 + (t>>1);
    float w = ((t&1)?wx:(1.f-wx)) * ((t>>1)?wy:(1.f-wy));
    if (xi>=0 && xi<152 && yi>=0 && yi<100) {
      accv += w * x2[((size_t)(n*LQ + yi*152 + xi))*D_MODEL + d];
    }
  }
  pf[(size_t)pidx*D_MODEL + d] = accv;
}

__global__ void copy_gt(const int* __restrict__ gt, float* __restrict__ out, int nels)
{
  int i = blockIdx.x*256 + threadIdx.x;
  if (i < nels) out[i] = (float)gt[i];
}

extern "C" void kernel_launch(void* const* d_in, const int* in_sizes, int n_in,
                              void* d_out, int out_size, void* d_ws, size_t ws_size,
                              hipStream_t stream)
{
  const float* feat[3]  = {(const float*)d_in[0], (const float*)d_in[1], (const float*)d_in[2]};
  const float* pc       = (const float*)d_in[3];
  const int*   gt       = (const int*)d_in[4];
  const float* projw[3] = {(const float*)d_in[5],  (const float*)d_in[9],  (const float*)d_in[13]};
  const float* projb[3] = {(const float*)d_in[6],  (const float*)d_in[10], (const float*)d_in[14]};
  const float* gng[3]   = {(const float*)d_in[7],  (const float*)d_in[11], (const float*)d_in[15]};
  const float* gnb[3]   = {(const float*)d_in[8],  (const float*)d_in[12], (const float*)d_in[16]};
  const float* level_embed = (const float*)d_in[17];
  const float* w_off  = (const float*)d_in[18];
  const float* b_off  = (const float*)d_in[19];
  const float* w_attn = (const float*)d_in[20];
  const float* b_attn = (const float*)d_in[21];
  const float* w_val  = (const float*)d_in[22];
  const float* b_val  = (const float*)d_in[23];
  const float* w_out  = (const float*)d_in[24];
  const float* b_out  = (const float*)d_in[25];
  const float* ln1g   = (const float*)d_in[26];
  const float* ln1b   = (const float*)d_in[27];
  const float* ln2g   = (const float*)d_in[28];
  const float* ln2b   = (const float*)d_in[29];
  const float* wff1   = (const float*)d_in[30];
  const float* bff1   = (const float*)d_in[31];
  const float* wff2   = (const float*)d_in[32];
  const float* bff2   = (const float*)d_in[33];
  const float* fcw    = (const float*)d_in[34];
  const float* fcb    = (const float*)d_in[35];

  // ---- workspace layout (float units; total 47,241,728 f = 189 MB) ----
  float* ws    = (float*)d_ws;
  float* s_tmp = ws;                         // 10,214,400 (proj-out / attn_out / ffn2-out)
  float* srcb  = s_tmp + 10214400;           // 10,214,400 (src; later x2)
  float* offaw = srcb  + 10214400;           // 11,491,200 (off 7,660,800 + aw 3,830,400; later x fp32)
  unsigned short* value_b = (unsigned short*)(offaw + 11491200); // 10,214,400 bf16
  unsigned short* acc_b   = value_b + 10214400;                  // 10,214,400 bf16; later pf fp32
  unsigned short* q_b     = acc_b   + 10214400;                  // 10,214,400 bf16; later ffn h chunk
  float* stats = (float*)(q_b + 10214400);   // 128
  float* offbuf = offaw;
  float* awbuf  = offaw + 7660800;
  float* xbuf   = offaw;                     // x fp32 after deform
  float* pf     = (float*)acc_b;             // pf fp32 after out-proj

  const int HWs[3]  = {15200, 3800, 950};
  const int Cins[3] = {512, 1024, 2048};
  const int LOFF[3] = {0, 15200, 19000};

  // 1) per-level projection (bf16 MFMA) + GN + transpose
  for (int l = 0; l < 3; ++l) {
    int HW = HWs[l], K = Cins[l];
    mgemm<false,true,false,false,true><<<dim3((HW+63)/64, 4, NBATCH), 256, 0, stream>>>(
        projw[l], feat[l], projb[l], s_tmp, D_MODEL, HW, K, K, HW,
        (long)K*HW, (long)D_MODEL*HW);
    gn_reduce<<<dim3(32, NBATCH), 256, 0, stream>>>(s_tmp, stats, HW);
    gn_apply<<<dim3((HW+31)/32, 8, NBATCH), 256, 0, stream>>>(
        s_tmp, stats, gng[l], gnb[l], srcb, HW, LOFF[l]);
  }

  // 2) q = bf16(src + pos)
  compute_q<<<NT, 256, 0, stream>>>(srcb, level_embed, q_b);

  // 3) value / offsets / attention logits
  int gy = (NT + 63) / 64;
  mgemm<false,false,true, false,false><<<dim3(4, gy), 256, 0, stream>>>(
      srcb, w_val, b_val, value_b, NT, 256, 256, 256, 256, 0, 0);
  mgemm<true, false,false,false,false><<<dim3(3, gy), 256, 0, stream>>>(
      q_b, w_off, b_off, offbuf, NT, 192, 256, 256, 256, 0, 0);
  mgemm<true, false,false,false,false><<<dim3(2, gy), 256, 0, stream>>>(
      q_b, w_attn, b_attn, awbuf, NT, 96, 256, 256, 256, 0, 0);

  // 4) deformable sampling (softmax fused) -> acc bf16
  deform_sample<<<(NT*8*4 + 255)/256, 256, 0, stream>>>(value_b, offbuf, awbuf, acc_b);

  // 5) out-proj ; x = LN(src + attn) -> xbuf (offaw region, off/aw now dead)
  mgemm<true,false,false,false,false><<<dim3(4, gy), 256, 0, stream>>>(
      acc_b, w_out, b_out, s_tmp, NT, 256, 256, 256, 256, 0, 0);
  ln_add<<<(NT+3)/4, 256, 0, stream>>>(srcb, s_tmp, ln1g, ln1b, xbuf, NT);

  // 6) FFN chunked: h = relu(x@W1^T) bf16 (q_b region) ; y -> s_tmp
  unsigned short* hbuf = q_b;
  for (int c0 = 0; c0 < NT; c0 += 8192) {
    int mc = NT - c0; if (mc > 8192) mc = 8192;
    int gyc = (mc + 63) / 64;
    mgemm<false,false,true, true, false><<<dim3(16, gyc), 256, 0, stream>>>(
        xbuf + (size_t)c0*256, wff1, bff1, hbuf, mc, 1024, 256, 256, 256, 0, 0);
    mgemm<true, false,false,false,false><<<dim3(4, gyc), 256, 0, stream>>>(
        hbuf, wff2, bff2, s_tmp + (size_t)c0*256, mc, 256, 1024, 1024, 1024, 0, 0);
  }

  // 7) x2 = LN(x + y) -> srcb
  ln_add<<<(NT+3)/4, 256, 0, stream>>>(xbuf, s_tmp, ln2g, ln2b, srcb, NT);

  // 8) point bilinear -> pf fp32 (acc region), fc GEMM -> d_out, gt tail
  point_sample<<<2000, 256, 0, stream>>>(srcb, pc, pf);
  mgemm<false,false,false,true,false><<<dim3(12544/64, (2000+63)/64), 256, 0, stream>>>(
      pf, fcw, fcb, (float*)d_out, 2000, 12544, 256, 256, 256, 0, 0);
  copy_gt<<<8, 256, 0, stream>>>(gt, (float*)d_out + (size_t)2000*12544, 2000);
}

// Round 3
// 780.975 us; speedup vs baseline: 3.0126x; 1.1785x over previous
//
#include <hip/hip_runtime.h>
#include <cstddef>
#include <cstdint>

#define D_MODEL 256
#define LQ 19950
#define NBATCH 2
#define NT (NBATCH*LQ)

typedef short  bf16x8 __attribute__((ext_vector_type(8)));
typedef float  f32x4  __attribute__((ext_vector_type(4)));
typedef unsigned short u16x8 __attribute__((ext_vector_type(8)));

__device__ __forceinline__ unsigned short f2b(float f) {
  unsigned u = __float_as_uint(f);
  u += 0x7fff + ((u >> 16) & 1);          // RNE
  return (unsigned short)(u >> 16);
}
__device__ __forceinline__ float b2f(unsigned short s) {
  return __uint_as_float(((unsigned)s) << 16);
}
__device__ __forceinline__ bf16x8 pack8(float4 a, float4 b) {
  bf16x8 r;
  r[0]=(short)f2b(a.x); r[1]=(short)f2b(a.y); r[2]=(short)f2b(a.z); r[3]=(short)f2b(a.w);
  r[4]=(short)f2b(b.x); r[5]=(short)f2b(b.y); r[6]=(short)f2b(b.z); r[7]=(short)f2b(b.w);
  return r;
}

__device__ __forceinline__ void tok_level(int tok, int& H, int& W, int& loff, int& lvl) {
  if (tok < 15200)      { lvl=0; H=100; W=152; loff=0; }
  else if (tok < 19000) { lvl=1; H=50;  W=76;  loff=15200; }
  else                  { lvl=2; H=25;  W=38;  loff=19000; }
}

// ================= unified bf16-MFMA GEMM =================
// C[M,N] = A[M,K] * B + bias (+relu). A: fp32 or bf16 (ABF).
// B always fp32 source: BKN=false -> B[N,K] row-major (B^T form, weights)
//                       BKN=true  -> B[K,N] row-major (proj feature maps)
// C: fp32 or bf16 (CBF). ROWBIAS: bias indexed by M (proj), else by N.
template<bool ABF, bool BKN, bool CBF, bool RELU, bool ROWBIAS>
__global__ __launch_bounds__(256) void mgemm(
    const void* __restrict__ Av, const float* __restrict__ Bv,
    const float* __restrict__ bias, void* __restrict__ Cv,
    int M, int N, int K, int lda, int ldb, long sB, long sC)
{
  __shared__ unsigned short As[64][72];
  __shared__ unsigned short Bs[64][72];
  const int tid = threadIdx.x;
  const float* Bp = Bv + (size_t)blockIdx.z * sB;
  const int n0 = blockIdx.x * 64, m0 = blockIdx.y * 64;
  const int lane = tid & 63;
  const int wave = tid >> 6;
  const int l15 = lane & 15, q = lane >> 4;
  const int m_off = (wave >> 1) * 32, n_off = (wave & 1) * 32;
  f32x4 acc[2][2] = {};

  for (int k0 = 0; k0 < K; k0 += 64) {
    {
      int row = tid >> 2, kc = (tid & 3) * 8;
      int gm = m0 + row;
      bf16x8 v0 = (bf16x8)0, v1 = (bf16x8)0;
      if (gm < M) {
        if constexpr (ABF) {
          const unsigned short* A = (const unsigned short*)Av;
          v0 = *(const bf16x8*)&A[(size_t)gm*lda + k0 + kc];
          v1 = *(const bf16x8*)&A[(size_t)gm*lda + k0 + kc + 32];
        } else {
          const float* A = (const float*)Av;
          const float* p = &A[(size_t)gm*lda + k0 + kc];
          v0 = pack8(*(const float4*)p,      *(const float4*)(p+4));
          v1 = pack8(*(const float4*)(p+32), *(const float4*)(p+36));
        }
      }
      *(bf16x8*)&As[row][kc]    = v0;
      *(bf16x8*)&As[row][kc+32] = v1;
    }
    if constexpr (!BKN) {
      int row = tid >> 2, kc = (tid & 3) * 8;
      int gn = n0 + row;
      bf16x8 v0 = (bf16x8)0, v1 = (bf16x8)0;
      if (gn < N) {
        const float* p = &Bp[(size_t)gn*ldb + k0 + kc];
        v0 = pack8(*(const float4*)p,      *(const float4*)(p+4));
        v1 = pack8(*(const float4*)(p+32), *(const float4*)(p+36));
      }
      *(bf16x8*)&Bs[row][kc]    = v0;
      *(bf16x8*)&Bs[row][kc+32] = v1;
    } else {
      int kr = tid >> 3, nc = (tid & 7) * 8;
      #pragma unroll
      for (int half = 0; half < 2; ++half) {
        int kk = kr + half*32;
        const float* p = &Bp[(size_t)(k0+kk)*ldb + n0 + nc];
        float v[8];
        if (n0 + nc + 7 < N) {
          float2 a0 = *(const float2*)p,     a1 = *(const float2*)(p+2);
          float2 a2 = *(const float2*)(p+4), a3 = *(const float2*)(p+6);
          v[0]=a0.x; v[1]=a0.y; v[2]=a1.x; v[3]=a1.y;
          v[4]=a2.x; v[5]=a2.y; v[6]=a3.x; v[7]=a3.y;
        } else {
          #pragma unroll
          for (int i=0;i<8;++i) v[i] = (n0+nc+i < N) ? p[i] : 0.f;
        }
        #pragma unroll
        for (int i=0;i<8;++i) Bs[nc+i][kk] = f2b(v[i]);
      }
    }
    __syncthreads();
    #pragma unroll
    for (int s = 0; s < 2; ++s) {
      bf16x8 a0 = *(const bf16x8*)&As[m_off      + l15][s*32 + q*8];
      bf16x8 a1 = *(const bf16x8*)&As[m_off + 16 + l15][s*32 + q*8];
      bf16x8 b0 = *(const bf16x8*)&Bs[n_off      + l15][s*32 + q*8];
      bf16x8 b1 = *(const bf16x8*)&Bs[n_off + 16 + l15][s*32 + q*8];
      acc[0][0] = __builtin_amdgcn_mfma_f32_16x16x32_bf16(a0, b0, acc[0][0], 0,0,0);
      acc[0][1] = __builtin_amdgcn_mfma_f32_16x16x32_bf16(a0, b1, acc[0][1], 0,0,0);
      acc[1][0] = __builtin_amdgcn_mfma_f32_16x16x32_bf16(a1, b0, acc[1][0], 0,0,0);
      acc[1][1] = __builtin_amdgcn_mfma_f32_16x16x32_bf16(a1, b1, acc[1][1], 0,0,0);
    }
    __syncthreads();
  }
  float* Cf = (float*)Cv + (size_t)blockIdx.z * sC;
  unsigned short* Cb = (unsigned short*)Cv + (size_t)blockIdx.z * sC;
  #pragma unroll
  for (int r = 0; r < 2; ++r) {
    #pragma unroll
    for (int c = 0; c < 2; ++c) {
      #pragma unroll
      for (int v = 0; v < 4; ++v) {
        int gm = m0 + m_off + r*16 + q*4 + v;
        int gn = n0 + n_off + c*16 + l15;
        if (gm < M && gn < N) {
          float o = acc[r][c][v];
          if (bias) o += ROWBIAS ? bias[gm] : bias[gn];
          if (RELU) o = fmaxf(o, 0.f);
          if constexpr (CBF) Cb[(size_t)gm*N + gn] = f2b(o);
          else               Cf[(size_t)gm*N + gn] = o;
        }
      }
    }
  }
}

// ---------- GN stage 1: partial sums, grid (32 groups, N, 8 chunks) ----------
__global__ __launch_bounds__(256) void gn_partial(
    const float* __restrict__ s, float* __restrict__ partials, int HW)
{
  int g = blockIdx.x, n = blockIdx.y, c = blockIdx.z;
  const float4* base = (const float4*)(s + ((size_t)n*D_MODEL + g*8) * HW);
  int nvec = (8*HW) >> 2;
  float sum = 0.f, sq = 0.f;
  for (int j = c*256 + threadIdx.x; j < nvec; j += 2048) {
    float4 v = base[j];
    sum += v.x+v.y+v.z+v.w;
    sq  += v.x*v.x+v.y*v.y+v.z*v.z+v.w*v.w;
  }
  #pragma unroll
  for (int m=32;m;m>>=1){ sum += __shfl_xor(sum,m,64); sq += __shfl_xor(sq,m,64); }
  __shared__ float s1[4], s2[4];
  int w = threadIdx.x >> 6;
  if ((threadIdx.x & 63) == 0) { s1[w]=sum; s2[w]=sq; }
  __syncthreads();
  if (threadIdx.x == 0) {
    partials[(((size_t)n*32+g)*8 + c)*2]     = s1[0]+s1[1]+s1[2]+s1[3];
    partials[(((size_t)n*32+g)*8 + c)*2 + 1] = s2[0]+s2[1]+s2[2]+s2[3];
  }
}

// ---------- GN stage 2: finalize mu/rstd, 1 block of 64 threads ----------
__global__ __launch_bounds__(64) void gn_finalize(
    const float* __restrict__ partials, float* __restrict__ stats, int HW)
{
  int t = threadIdx.x;           // t = n*32+g, 64 entries
  float S = 0.f, Q = 0.f;
  #pragma unroll
  for (int c = 0; c < 8; ++c) {
    S += partials[((size_t)t*8 + c)*2];
    Q += partials[((size_t)t*8 + c)*2 + 1];
  }
  float inv = 1.f/(float)(8*HW);
  float mu = S*inv;
  float var = Q*inv - mu*mu;
  stats[(size_t)t*2]   = mu;
  stats[(size_t)t*2+1] = rsqrtf(var + 1e-5f);
}

// ---------- apply GN + transpose (n,o,hw) -> src[(n*LQ+loff+hw)*256+o] ----------
__global__ __launch_bounds__(256) void gn_apply(
    const float* __restrict__ s, const float* __restrict__ stats,
    const float* __restrict__ gw, const float* __restrict__ gb,
    float* __restrict__ src, int HW, int loff)
{
  __shared__ float T[32][33];
  int tx = threadIdx.x & 31, ty = threadIdx.x >> 5;
  int hw0 = blockIdx.x*32, o0 = blockIdx.y*32, n = blockIdx.z;
  const float* base = s + (size_t)n*D_MODEL*HW;
  #pragma unroll
  for (int it=0; it<4; ++it) {
    int ol = ty + it*8;
    int o = o0 + ol;
    int hw = hw0 + tx;
    float v = 0.f;
    if (hw < HW) {
      int grp = o >> 3;
      float mu   = stats[((size_t)n*32+grp)*2];
      float rstd = stats[((size_t)n*32+grp)*2+1];
      v = (base[(size_t)o*HW + hw] - mu)*rstd*gw[o] + gb[o];
    }
    T[ol][tx] = v;
  }
  __syncthreads();
  #pragma unroll
  for (int it=0; it<4; ++it) {
    int tl = ty + it*8;
    int tok = hw0 + tl;
    if (tok < HW) {
      src[((size_t)n*LQ + loff + tok)*D_MODEL + o0 + tx] = T[tx][tl];
    }
  }
}

// ---------- q = bf16(src + sine_pos + level_embed) ----------
__global__ __launch_bounds__(256) void compute_q(
    const float* __restrict__ src, const float* __restrict__ level_embed,
    unsigned short* __restrict__ q)
{
  int row = blockIdx.x;
  int d = threadIdx.x;
  int tok = row % LQ;
  int H,W,loff,lvl; tok_level(tok,H,W,loff,lvl);
  int hw = tok - loff;
  int i = hw / W, j = hw % W;
  const float TWO_PI = 6.28318530717958647692f;
  float yv = (float)(i+1) / ((float)H + 1e-6f) * TWO_PI;
  float xv = (float)(j+1) / ((float)W + 1e-6f) * TWO_PI;
  int m = (d & 127) >> 1;
  float t = powf(10000.0f, (float)m * (1.0f/64.0f));
  float ang = ((d < 128) ? yv : xv) / t;
  float pe = (d & 1) ? cosf(ang) : sinf(ang);
  size_t idx = (size_t)row*D_MODEL + d;
  q[idx] = f2b(src[idx] + pe + level_embed[lvl*D_MODEL + d]);
}

// ---------- deformable sampling (bf16 value, softmax fused) ----------
__global__ __launch_bounds__(256) void deform_sample(
    const unsigned short* __restrict__ value, const float* __restrict__ offb,
    const float* __restrict__ awb, unsigned short* __restrict__ accb)
{
  int idx = blockIdx.x*256 + threadIdx.x;
  if (idx >= NT*8*4) return;
  int quarter = idx & 3;
  int h = (idx >> 2) & 7;
  int row = idx >> 5;
  int tok = row % LQ;
  int n = row / LQ;
  int Ht,Wt,lofft,lvlt; tok_level(tok,Ht,Wt,lofft,lvlt);
  int hw = tok - lofft;
  int ti = hw / Wt, tj = hw % Wt;
  float gxr = ((float)tj + 0.5f) / (float)Wt;
  float gyr = ((float)ti + 0.5f) / (float)Ht;
  const float* offr = offb + (size_t)row*192 + h*24;
  const float* awr  = awb  + (size_t)row*96  + h*12;
  float lg[12];
  float mx = -1e30f;
  #pragma unroll
  for (int i=0;i<12;++i){ lg[i]=awr[i]; mx = fmaxf(mx, lg[i]); }
  float ssum = 0.f;
  #pragma unroll
  for (int i=0;i<12;++i){ lg[i] = __expf(lg[i]-mx); ssum += lg[i]; }
  float sinv = 1.f/ssum;
  float acc[8] = {0.f,0.f,0.f,0.f,0.f,0.f,0.f,0.f};
  const int HH[3]={100,50,25}, WW[3]={152,76,38}, OO[3]={0,15200,19000};
  int chbase = h*32 + quarter*8;
  #pragma unroll
  for (int lvl=0; lvl<3; ++lvl) {
    const int H=HH[lvl], W=WW[lvl], lo=OO[lvl];
    #pragma unroll
    for (int p=0; p<4; ++p) {
      float ox = offr[lvl*8 + p*2];
      float oy = offr[lvl*8 + p*2 + 1];
      float a  = lg[lvl*4 + p] * sinv;
      float locx = gxr + ox / (float)W;
      float locy = gyr + oy / (float)H;
      float x = ((2.f*locx) * (float)W - 1.f) * 0.5f;
      float y = ((2.f*locy) * (float)H - 1.f) * 0.5f;
      float x0f = floorf(x), y0f = floorf(y);
      float wx = x - x0f, wy = y - y0f;
      int x0 = (int)x0f, y0 = (int)y0f;
      float tw[4] = { (1.f-wx)*(1.f-wy)*a, wx*(1.f-wy)*a, (1.f-wx)*wy*a, wx*wy*a };
      #pragma unroll
      for (int t=0; t<4; ++t) {
        int xi = x0 + (t & 1), yi = y0 + (t >> 1);
        if (xi >= 0 && xi < W && yi >= 0 && yi < H) {
          const float w = tw[t];
          const unsigned short* vr = value + ((size_t)(n*LQ + lo + yi*W + xi)*D_MODEL + chbase);
          u16x8 v = *(const u16x8*)vr;
          #pragma unroll
          for (int jj=0;jj<8;++jj) acc[jj] += w * b2f(v[jj]);
        }
      }
    }
  }
  unsigned short* o = accb + (size_t)row*D_MODEL + chbase;
  u16x8 ov;
  #pragma unroll
  for (int jj=0;jj<8;++jj) ov[jj] = f2b(acc[jj]);
  *(u16x8*)o = ov;
}

// ---------- out = LN(A+B)*g+b, row length 256, one wave per row ----------
__global__ __launch_bounds__(256) void ln_add(
    const float* __restrict__ A, const float* __restrict__ B,
    const float* __restrict__ g, const float* __restrict__ b,
    float* __restrict__ out, int rows)
{
  int wid = (blockIdx.x * 256 + threadIdx.x) >> 6;
  int lane = threadIdx.x & 63;
  if (wid >= rows) return;
  size_t base = (size_t)wid * D_MODEL;
  float4 va = *(const float4*)&A[base + lane*4];
  float4 vb = *(const float4*)&B[base + lane*4];
  float v[4] = {va.x+vb.x, va.y+vb.y, va.z+vb.z, va.w+vb.w};
  float s = v[0]+v[1]+v[2]+v[3];
  #pragma unroll
  for (int m=32; m; m>>=1) s += __shfl_xor(s, m, 64);
  float mu = s * (1.f/256.f);
  float qq = 0.f;
  #pragma unroll
  for (int i=0;i<4;++i){ float d=v[i]-mu; qq += d*d; }
  #pragma unroll
  for (int m=32; m; m>>=1) qq += __shfl_xor(qq, m, 64);
  float rstd = rsqrtf(qq*(1.f/256.f) + 1e-5f);
  #pragma unroll
  for (int i=0;i<4;++i){
    int d = lane*4+i;
    out[base+d] = (v[i]-mu)*rstd*g[d] + b[d];
  }
}

// ---------- point head bilinear sample from level-0 tokens ----------
__global__ __launch_bounds__(256) void point_sample(
    const float* __restrict__ x2, const float* __restrict__ pc,
    float* __restrict__ pf)
{
  int pidx = blockIdx.x;
  int n = pidx / 1000;
  float px = pc[(size_t)pidx*2], py = pc[(size_t)pidx*2+1];
  float x = ((2.f*px)*152.f - 1.f)*0.5f;
  float y = ((2.f*py)*100.f - 1.f)*0.5f;
  float x0f=floorf(x), y0f=floorf(y);
  float wx=x-x0f, wy=y-y0f;
  int x0=(int)x0f, y0=(int)y0f;
  int d = threadIdx.x;
  float accv = 0.f;
  #pragma unroll
  for (int t=0;t<4;++t) {
    int xi = x0 + (t&1), yi = y0 + (t>>1);
    float w = ((t&1)?wx:(1.f-wx)) * ((t>>1)?wy:(1.f-wy));
    if (xi>=0 && xi<152 && yi>=0 && yi<100) {
      accv += w * x2[((size_t)(n*LQ + yi*152 + xi))*D_MODEL + d];
    }
  }
  pf[(size_t)pidx*D_MODEL + d] = accv;
}

__global__ void copy_gt(const int* __restrict__ gt, float* __restrict__ out, int nels)
{
  int i = blockIdx.x*256 + threadIdx.x;
  if (i < nels) out[i] = (float)gt[i];
}

extern "C" void kernel_launch(void* const* d_in, const int* in_sizes, int n_in,
                              void* d_out, int out_size, void* d_ws, size_t ws_size,
                              hipStream_t stream)
{
  const float* feat[3]  = {(const float*)d_in[0], (const float*)d_in[1], (const float*)d_in[2]};
  const float* pc       = (const float*)d_in[3];
  const int*   gt       = (const int*)d_in[4];
  const float* projw[3] = {(const float*)d_in[5],  (const float*)d_in[9],  (const float*)d_in[13]};
  const float* projb[3] = {(const float*)d_in[6],  (const float*)d_in[10], (const float*)d_in[14]};
  const float* gng[3]   = {(const float*)d_in[7],  (const float*)d_in[11], (const float*)d_in[15]};
  const float* gnb[3]   = {(const float*)d_in[8],  (const float*)d_in[12], (const float*)d_in[16]};
  const float* level_embed = (const float*)d_in[17];
  const float* w_off  = (const float*)d_in[18];
  const float* b_off  = (const float*)d_in[19];
  const float* w_attn = (const float*)d_in[20];
  const float* b_attn = (const float*)d_in[21];
  const float* w_val  = (const float*)d_in[22];
  const float* b_val  = (const float*)d_in[23];
  const float* w_out  = (const float*)d_in[24];
  const float* b_out  = (const float*)d_in[25];
  const float* ln1g   = (const float*)d_in[26];
  const float* ln1b   = (const float*)d_in[27];
  const float* ln2g   = (const float*)d_in[28];
  const float* ln2b   = (const float*)d_in[29];
  const float* wff1   = (const float*)d_in[30];
  const float* bff1   = (const float*)d_in[31];
  const float* wff2   = (const float*)d_in[32];
  const float* bff2   = (const float*)d_in[33];
  const float* fcw    = (const float*)d_in[34];
  const float* fcb    = (const float*)d_in[35];

  // ---- workspace layout (float units) ----
  float* ws    = (float*)d_ws;
  float* s_tmp = ws;                         // 10,214,400
  float* srcb  = s_tmp + 10214400;           // 10,214,400
  float* offaw = srcb  + 10214400;           // 11,491,200
  unsigned short* value_b = (unsigned short*)(offaw + 11491200); // 10,214,400 bf16
  unsigned short* acc_b   = value_b + 10214400;                  // 10,214,400 bf16
  unsigned short* q_b     = acc_b   + 10214400;                  // 10,214,400 bf16
  float* stats    = (float*)(q_b + 10214400);   // 128
  float* partials = stats + 128;                // 1024
  float* offbuf = offaw;
  float* awbuf  = offaw + 7660800;
  float* xbuf   = offaw;
  float* pf     = (float*)acc_b;

  const int HWs[3]  = {15200, 3800, 950};
  const int Cins[3] = {512, 1024, 2048};
  const int LOFF[3] = {0, 15200, 19000};

  // 1) per-level projection (bf16 MFMA) + GN + transpose
  for (int l = 0; l < 3; ++l) {
    int HW = HWs[l], K = Cins[l];
    mgemm<false,true,false,false,true><<<dim3((HW+63)/64, 4, NBATCH), 256, 0, stream>>>(
        projw[l], feat[l], projb[l], s_tmp, D_MODEL, HW, K, K, HW,
        (long)K*HW, (long)D_MODEL*HW);
    gn_partial<<<dim3(32, NBATCH, 8), 256, 0, stream>>>(s_tmp, partials, HW);
    gn_finalize<<<1, 64, 0, stream>>>(partials, stats, HW);
    gn_apply<<<dim3((HW+31)/32, 8, NBATCH), 256, 0, stream>>>(
        s_tmp, stats, gng[l], gnb[l], srcb, HW, LOFF[l]);
  }

  // 2) q = bf16(src + pos)
  compute_q<<<NT, 256, 0, stream>>>(srcb, level_embed, q_b);

  // 3) value / offsets / attention logits
  int gy = (NT + 63) / 64;
  mgemm<false,false,true, false,false><<<dim3(4, gy), 256, 0, stream>>>(
      srcb, w_val, b_val, value_b, NT, 256, 256, 256, 256, 0, 0);
  mgemm<true, false,false,false,false><<<dim3(3, gy), 256, 0, stream>>>(
      q_b, w_off, b_off, offbuf, NT, 192, 256, 256, 256, 0, 0);
  mgemm<true, false,false,false,false><<<dim3(2, gy), 256, 0, stream>>>(
      q_b, w_attn, b_attn, awbuf, NT, 96, 256, 256, 256, 0, 0);

  // 4) deformable sampling (softmax fused) -> acc bf16
  deform_sample<<<(NT*8*4 + 255)/256, 256, 0, stream>>>(value_b, offbuf, awbuf, acc_b);

  // 5) out-proj ; x = LN(src + attn) -> xbuf
  mgemm<true,false,false,false,false><<<dim3(4, gy), 256, 0, stream>>>(
      acc_b, w_out, b_out, s_tmp, NT, 256, 256, 256, 256, 0, 0);
  ln_add<<<(NT+3)/4, 256, 0, stream>>>(srcb, s_tmp, ln1g, ln1b, xbuf, NT);

  // 6) FFN chunked
  unsigned short* hbuf = q_b;
  for (int c0 = 0; c0 < NT; c0 += 8192) {
    int mc = NT - c0; if (mc > 8192) mc = 8192;
    int gyc = (mc + 63) / 64;
    mgemm<false,false,true, true, false><<<dim3(16, gyc), 256, 0, stream>>>(
        xbuf + (size_t)c0*256, wff1, bff1, hbuf, mc, 1024, 256, 256, 256, 0, 0);
    mgemm<true, false,false,false,false><<<dim3(4, gyc), 256, 0, stream>>>(
        hbuf, wff2, bff2, s_tmp + (size_t)c0*256, mc, 256, 1024, 1024, 1024, 0, 0);
  }

  // 7) x2 = LN(x + y) -> srcb
  ln_add<<<(NT+3)/4, 256, 0, stream>>>(xbuf, s_tmp, ln2g, ln2b, srcb, NT);

  // 8) point bilinear -> pf, fc GEMM -> d_out, gt tail
  point_sample<<<2000, 256, 0, stream>>>(srcb, pc, pf);
  mgemm<false,false,false,true,false><<<dim3(12544/64, (2000+63)/64), 256, 0, stream>>>(
      pf, fcw, fcb, (float*)d_out, 2000, 12544, 256, 256, 256, 0, 0);
  copy_gt<<<8, 256, 0, stream>>>(gt, (float*)d_out + (size_t)2000*12544, 2000);
}